// Round 3
// baseline (127.087 us; speedup 1.0000x reference)
//
#include <hip/hip_runtime.h>

#define POOL 7
#define NUM_ROIS 300
#define H_IMG 200
#define W_IMG 200
#define C_IMG 512
#define CHUNKS_PER_CELL (C_IMG / 4)                 // 128 float4 chunks per output cell
#define NCELL (NUM_ROIS * POOL * POOL)              // 14700
#define NCHUNK (NCELL * CHUNKS_PER_CELL)            // 1,881,600
#define UNROLL 4
#define TPB 256

// Native clang vector type: __builtin_nontemporal_store requires it
// (HIP's float4 is a class and is rejected).
typedef float fx4 __attribute__((ext_vector_type(4)));

// Grid-stride with 4 independent (cell, chunk) items per thread: 16 global
// loads in flight per thread to hide cold-HBM latency (poison fills evict
// the image from L3 before every timed replay). Channel chunks are the
// fastest-varying index -> consecutive lanes read consecutive 16B -> fully
// coalesced. Addresses kept as 32-bit float4 indices (img = 82 MB < 2^31 B)
// to limit VGPR pressure.
__global__ __launch_bounds__(TPB) void roi_pool_kernel(
    const float* __restrict__ img,
    const float* __restrict__ rois,
    float* __restrict__ out)
{
    const fx4* __restrict__ img4 = (const fx4*)img;
    fx4* __restrict__ out4 = (fx4*)out;

    const int stride = gridDim.x * TPB;
    const int g0 = blockIdx.x * TPB + threadIdx.x;

    int  valid[UNROLL];
    int  i00[UNROLL], i01[UNROLL], i10[UNROLL], i11[UNROLL];
    int  idst[UNROLL];
    float fxa[UNROLL], fya[UNROLL];

    #pragma unroll
    for (int k = 0; k < UNROLL; ++k) {
        const int g = g0 + k * stride;
        valid[k] = (g < NCHUNK);
        const int gc = valid[k] ? g : 0;

        const int cell = gc >> 7;              // / CHUNKS_PER_CELL
        const int ch4  = gc & 127;             // float4 index within channels
        const int roi  = cell / (POOL * POOL);
        const int rc   = cell - roi * (POOL * POOL);
        const int py   = rc / POOL;
        const int px   = rc - py * POOL;

        const float rx = rois[roi * 4 + 0];
        const float ry = rois[roi * 4 + 1];
        const float rw = rois[roi * 4 + 2];
        const float rh = rois[roi * 4 + 3];

        // reference clip order (truncating int casts)
        const int x0 = min(max((int)rx, 0), W_IMG - 1);
        const int y0 = min(max((int)ry, 0), H_IMG - 1);
        const int w  = min(max((int)rw, 1), W_IMG - x0);
        const int h  = min(max((int)rh, 1), H_IMG - y0);

        // TF1 resize (align_corners=False): src = dst * (in/out)
        const float xs = (float)px * ((float)w / (float)POOL);
        const float ys = (float)py * ((float)h / (float)POOL);
        int ix0 = (int)floorf(xs);
        int iy0 = (int)floorf(ys);
        fxa[k] = xs - (float)ix0;              // before the clamp (matches ref)
        fya[k] = ys - (float)iy0;
        ix0 = min(ix0, w - 1);
        iy0 = min(iy0, h - 1);
        const int ix1 = min(ix0 + 1, w - 1);
        const int iy1 = min(iy0 + 1, h - 1);

        const int ax0 = x0 + ix0;
        const int ax1 = x0 + ix1;
        const int ay0 = y0 + iy0;
        const int ay1 = y0 + iy1;

        // float4-granular indices into img
        i00[k] = (ay0 * W_IMG + ax0) * CHUNKS_PER_CELL + ch4;
        i01[k] = (ay0 * W_IMG + ax1) * CHUNKS_PER_CELL + ch4;
        i10[k] = (ay1 * W_IMG + ax0) * CHUNKS_PER_CELL + ch4;
        i11[k] = (ay1 * W_IMG + ax1) * CHUNKS_PER_CELL + ch4;
        idst[k] = cell * CHUNKS_PER_CELL + ch4;
    }

    // Issue all 16 loads before any compute -> maximum MLP.
    fx4 v00[UNROLL], v01[UNROLL], v10[UNROLL], v11[UNROLL];
    #pragma unroll
    for (int k = 0; k < UNROLL; ++k) {
        if (valid[k]) {
            v00[k] = img4[i00[k]];
            v01[k] = img4[i01[k]];
            v10[k] = img4[i10[k]];
            v11[k] = img4[i11[k]];
        }
    }

    #pragma unroll
    for (int k = 0; k < UNROLL; ++k) {
        if (valid[k]) {
            const float fx = fxa[k], fy = fya[k];
            const float gx = 1.0f - fx, gy = 1.0f - fy;
            fx4 o;
            o.x = (v00[k].x * gx + v01[k].x * fx) * gy + (v10[k].x * gx + v11[k].x * fx) * fy;
            o.y = (v00[k].y * gx + v01[k].y * fx) * gy + (v10[k].y * gx + v11[k].y * fx) * fy;
            o.z = (v00[k].z * gx + v01[k].z * fx) * gy + (v10[k].z * gx + v11[k].z * fx) * fy;
            o.w = (v00[k].w * gx + v01[k].w * fx) * gy + (v10[k].w * gx + v11[k].w * fx) * fy;
            __builtin_nontemporal_store(o, &out4[idst[k]]);   // output has zero reuse
        }
    }
}

extern "C" void kernel_launch(void* const* d_in, const int* in_sizes, int n_in,
                              void* d_out, int out_size, void* d_ws, size_t ws_size,
                              hipStream_t stream) {
    const float* img  = (const float*)d_in[0];   // (1,200,200,512) fp32
    const float* rois = (const float*)d_in[1];   // (1,300,4) fp32
    float* out = (float*)d_out;                  // (1,300,7,7,512) fp32

    const int nblocks = (NCHUNK + TPB * UNROLL - 1) / (TPB * UNROLL);  // 1838
    roi_pool_kernel<<<nblocks, TPB, 0, stream>>>(img, rois, out);
}

// Round 4
// 124.550 us; speedup vs baseline: 1.0204x; 1.0204x over previous
//
#include <hip/hip_runtime.h>

#define POOL 7
#define NUM_ROIS 300
#define H_IMG 200
#define W_IMG 200
#define C_IMG 512
#define CHUNKS_PER_CELL (C_IMG / 4)                 // 128 float4 chunks per output cell
#define NCELL (NUM_ROIS * POOL * POOL)              // 14700
#define NCHUNK (NCELL * CHUNKS_PER_CELL)            // 1,881,600
#define UNROLL 4
#define TPB 256
#define NBLK ((NCHUNK + TPB * UNROLL - 1) / (TPB * UNROLL))   // 1838 logical blocks
#define PER_XCD ((NBLK + 7) / 8)                    // 230
#define GRID (PER_XCD * 8)                          // 1840 launched blocks

typedef float fx4 __attribute__((ext_vector_type(4)));

// XCD-contiguity swizzle: hardware round-robins consecutive workgroups
// across the 8 XCDs (per-XCD L2s are not coherent/shared). Remap so XCD k
// processes a CONTIGUOUS span of logical blocks (≈37 consecutive ROIs):
// without this, the cells of one ROI scatter across all 8 XCDs and each
// XCD's 4MB L2 re-fetches the same corner lines (up to 8x fill
// amplification from L3/HBM on cold caches).
__global__ __launch_bounds__(TPB) void roi_pool_kernel(
    const float* __restrict__ img,
    const float* __restrict__ rois,
    float* __restrict__ out)
{
    const fx4* __restrict__ img4 = (const fx4*)img;
    fx4* __restrict__ out4 = (fx4*)out;

    const int b  = blockIdx.x;
    const int lb = (b & 7) * PER_XCD + (b >> 3);    // logical block, XCD-contiguous
    if (lb >= NBLK) return;

    const int stride = NBLK * TPB;                  // logical stride over chunks
    const int g0 = lb * TPB + threadIdx.x;

    int  valid[UNROLL];
    int  i00[UNROLL], i01[UNROLL], i10[UNROLL], i11[UNROLL];
    int  idst[UNROLL];
    float fxa[UNROLL], fya[UNROLL];

    #pragma unroll
    for (int k = 0; k < UNROLL; ++k) {
        const int g = g0 + k * stride;
        valid[k] = (g < NCHUNK);
        const int gc = valid[k] ? g : 0;

        const int cell = gc >> 7;              // / CHUNKS_PER_CELL
        const int ch4  = gc & 127;             // float4 index within channels
        const int roi  = cell / (POOL * POOL);
        const int rc   = cell - roi * (POOL * POOL);
        const int py   = rc / POOL;
        const int px   = rc - py * POOL;

        const float rx = rois[roi * 4 + 0];
        const float ry = rois[roi * 4 + 1];
        const float rw = rois[roi * 4 + 2];
        const float rh = rois[roi * 4 + 3];

        // reference clip order (truncating int casts)
        const int x0 = min(max((int)rx, 0), W_IMG - 1);
        const int y0 = min(max((int)ry, 0), H_IMG - 1);
        const int w  = min(max((int)rw, 1), W_IMG - x0);
        const int h  = min(max((int)rh, 1), H_IMG - y0);

        // TF1 resize (align_corners=False): src = dst * (in/out)
        const float xs = (float)px * ((float)w / (float)POOL);
        const float ys = (float)py * ((float)h / (float)POOL);
        int ix0 = (int)floorf(xs);
        int iy0 = (int)floorf(ys);
        fxa[k] = xs - (float)ix0;              // before the clamp (matches ref)
        fya[k] = ys - (float)iy0;
        ix0 = min(ix0, w - 1);
        iy0 = min(iy0, h - 1);
        const int ix1 = min(ix0 + 1, w - 1);
        const int iy1 = min(iy0 + 1, h - 1);

        const int ax0 = x0 + ix0;
        const int ax1 = x0 + ix1;
        const int ay0 = y0 + iy0;
        const int ay1 = y0 + iy1;

        // float4-granular indices into img
        i00[k] = (ay0 * W_IMG + ax0) * CHUNKS_PER_CELL + ch4;
        i01[k] = (ay0 * W_IMG + ax1) * CHUNKS_PER_CELL + ch4;
        i10[k] = (ay1 * W_IMG + ax0) * CHUNKS_PER_CELL + ch4;
        i11[k] = (ay1 * W_IMG + ax1) * CHUNKS_PER_CELL + ch4;
        idst[k] = cell * CHUNKS_PER_CELL + ch4;
    }

    // Issue all 16 loads before any compute -> maximum MLP.
    fx4 v00[UNROLL], v01[UNROLL], v10[UNROLL], v11[UNROLL];
    #pragma unroll
    for (int k = 0; k < UNROLL; ++k) {
        if (valid[k]) {
            v00[k] = img4[i00[k]];
            v01[k] = img4[i01[k]];
            v10[k] = img4[i10[k]];
            v11[k] = img4[i11[k]];
        }
    }

    #pragma unroll
    for (int k = 0; k < UNROLL; ++k) {
        if (valid[k]) {
            const float fx = fxa[k], fy = fya[k];
            const float gx = 1.0f - fx, gy = 1.0f - fy;
            fx4 o;
            o.x = (v00[k].x * gx + v01[k].x * fx) * gy + (v10[k].x * gx + v11[k].x * fx) * fy;
            o.y = (v00[k].y * gx + v01[k].y * fx) * gy + (v10[k].y * gx + v11[k].y * fx) * fy;
            o.z = (v00[k].z * gx + v01[k].z * fx) * gy + (v10[k].z * gx + v11[k].z * fx) * fy;
            o.w = (v00[k].w * gx + v01[k].w * fx) * gy + (v10[k].w * gx + v11[k].w * fx) * fy;
            __builtin_nontemporal_store(o, &out4[idst[k]]);   // output has zero reuse
        }
    }
}

extern "C" void kernel_launch(void* const* d_in, const int* in_sizes, int n_in,
                              void* d_out, int out_size, void* d_ws, size_t ws_size,
                              hipStream_t stream) {
    const float* img  = (const float*)d_in[0];   // (1,200,200,512) fp32
    const float* rois = (const float*)d_in[1];   // (1,300,4) fp32
    float* out = (float*)d_out;                  // (1,300,7,7,512) fp32

    roi_pool_kernel<<<GRID, TPB, 0, stream>>>(img, rois, out);
}